// Round 1
// baseline (260.801 us; speedup 1.0000x reference)
//
#include <hip/hip_runtime.h>

typedef unsigned short ushort_t;
typedef short bf16x8 __attribute__((ext_vector_type(8)));
typedef float f32x4 __attribute__((ext_vector_type(4)));

__device__ __forceinline__ unsigned short f2bf(float f) {
    unsigned u = __float_as_uint(f);
    u += 0x7FFFu + ((u >> 16) & 1u);      // round-to-nearest-even
    return (unsigned short)(u >> 16);
}
__device__ __forceinline__ float bf2f(unsigned short h) {
    return __uint_as_float(((unsigned)h) << 16);
}

__device__ __forceinline__ void gload_lds16(const void* g, void* l) {
    __builtin_amdgcn_global_load_lds(
        (const __attribute__((address_space(1))) void*)g,
        (__attribute__((address_space(3))) void*)l,
        16, 0, 0);
}

// ---------------------------------------------------------------- convert u -> bf16
__global__ void convert_u(const float4* __restrict__ u, unsigned short* __restrict__ A) {
    int i = blockIdx.x * 256 + threadIdx.x;   // indexes float4, 4.19M total
    float4 v = u[i];
    ushort4 o;
    o.x = f2bf(v.x); o.y = f2bf(v.y); o.z = f2bf(v.z); o.w = f2bf(v.w);
    ((ushort4*)A)[i] = o;
}

// ---------------------------------------------------------------- Bt[n][k] = (n<512? Br[k][n] : Bi[k][n-512])
// LDS 32x32 transpose; Br,Bi are (1024 x 512) row-major. Bt is 1024x1024 bf16.
__global__ void build_bt(const float* __restrict__ Br, const float* __restrict__ Bi,
                         unsigned short* __restrict__ Bt) {
    __shared__ unsigned short tile[32][33];
    int bk = blockIdx.x * 32;   // k block
    int bn = blockIdx.y * 32;   // n block
    int tx = threadIdx.x;       // 0..31
    int ty = threadIdx.y;       // 0..7
    for (int i = ty; i < 32; i += 8) {
        int k = bk + i;
        int n = bn + tx;
        float v = (n < 512) ? Br[k * 512 + n] : Bi[k * 512 + (n - 512)];
        tile[tx][i] = f2bf(v);
    }
    __syncthreads();
    for (int i = ty; i < 32; i += 8) {
        int n = bn + i;
        int k = bk + tx;
        Bt[(size_t)n * 1024 + k] = tile[i][tx];
    }
}

// ---------------------------------------------------------------- Dt[h][k2] = (k2<512? Cr[k2][h] : -Ci[k2-512][h])
// Cr,Ci are (512 x 1024) row-major. Dt is 1024x1024 bf16.
__global__ void build_dt(const float* __restrict__ Cr, const float* __restrict__ Ci,
                         unsigned short* __restrict__ Dt) {
    __shared__ unsigned short tile[32][33];
    int bk = blockIdx.x * 32;   // k2 block
    int bh = blockIdx.y * 32;   // h block
    int tx = threadIdx.x;
    int ty = threadIdx.y;
    for (int i = ty; i < 32; i += 8) {
        int k2 = bk + i;
        int h = bh + tx;
        float v = (k2 < 512) ? Cr[(size_t)k2 * 1024 + h] : -Ci[(size_t)(k2 - 512) * 1024 + h];
        tile[tx][i] = f2bf(v);
    }
    __syncthreads();
    for (int i = ty; i < 32; i += 8) {
        int h = bh + i;
        int k2 = bk + tx;
        Dt[(size_t)h * 1024 + k2] = tile[i][tx];
    }
}

// ---------------------------------------------------------------- GEMM: C(16384x1024) = A(16384x1024 bf16) x Bt(1024x1024 bf16, row=output col)
// m97 structure: 128x128 tile, BK=32, 4 waves in 2x2, 4x4 16x16x32 MFMA per wave,
// global_load_lds width=16 staging, single LDS buffer, 2 barriers per K-iter.
template <int OUTF32>
__global__ __launch_bounds__(256)
void gemm_bt(const unsigned short* __restrict__ A, const unsigned short* __restrict__ Bt,
             unsigned short* __restrict__ Cb, float* __restrict__ Cf) {
    __shared__ unsigned short As[128 * 32];   // [row][k] row-major, 8 KB
    __shared__ unsigned short Bs[128 * 32];   // [col][k] row-major, 8 KB

    const int tid  = threadIdx.x;
    const int wave = tid >> 6;
    const int lane = tid & 63;
    const int lm = lane & 15;
    const int lq = lane >> 4;
    const int wr = wave >> 1;   // 0..1
    const int wc = wave & 1;    // 0..1

    const int row0 = blockIdx.y * 128;
    const int col0 = blockIdx.x * 128;

    f32x4 acc[4][4] = {};

    // staging: flat byte offset within 8 KB tile; o = tid*16 (+4096 for issue 1)
    const int o0 = tid * 16;
    const int o1 = o0 + 4096;

    const char* gA0 = (const char*)A  + (size_t)(row0 + (o0 >> 6)) * 2048 + (o0 & 63);
    const char* gA1 = (const char*)A  + (size_t)(row0 + (o1 >> 6)) * 2048 + (o1 & 63);
    const char* gB0 = (const char*)Bt + (size_t)(col0 + (o0 >> 6)) * 2048 + (o0 & 63);
    const char* gB1 = (const char*)Bt + (size_t)(col0 + (o1 >> 6)) * 2048 + (o1 & 63);

    // LDS dest must be wave-uniform: base + lane*16 is done by HW
    char* lA0 = (char*)As + wave * 1024;
    char* lA1 = lA0 + 4096;
    char* lB0 = (char*)Bs + wave * 1024;
    char* lB1 = lB0 + 4096;

    for (int kk = 0; kk < 32; ++kk) {
        __syncthreads();                 // previous iter's LDS reads done
        gload_lds16(gA0, lA0);
        gload_lds16(gA1, lA1);
        gload_lds16(gB0, lB0);
        gload_lds16(gB1, lB1);
        gA0 += 64; gA1 += 64; gB0 += 64; gB1 += 64;
        __syncthreads();                 // vmcnt(0) drain + barrier: staging visible

        bf16x8 af[4], bfr[4];
#pragma unroll
        for (int mi = 0; mi < 4; ++mi) {
            int m = wr * 64 + mi * 16 + lm;
            af[mi] = *(const bf16x8*)(As + m * 32 + lq * 8);   // ds_read_b128
        }
#pragma unroll
        for (int ni = 0; ni < 4; ++ni) {
            int n = wc * 64 + ni * 16 + lm;
            bfr[ni] = *(const bf16x8*)(Bs + n * 32 + lq * 8);
        }
#pragma unroll
        for (int mi = 0; mi < 4; ++mi)
#pragma unroll
            for (int ni = 0; ni < 4; ++ni)
                acc[mi][ni] = __builtin_amdgcn_mfma_f32_16x16x32_bf16(
                    af[mi], bfr[ni], acc[mi][ni], 0, 0, 0);
    }

    // epilogue: C/D layout col=lane&15, row=(lane>>4)*4+reg  [m89/m91-verified]
#pragma unroll
    for (int mi = 0; mi < 4; ++mi) {
#pragma unroll
        for (int ni = 0; ni < 4; ++ni) {
            int c  = col0 + wc * 64 + ni * 16 + lm;
            int r0 = row0 + wr * 64 + mi * 16 + lq * 4;
#pragma unroll
            for (int r = 0; r < 4; ++r) {
                size_t off = (size_t)(r0 + r) * 1024 + c;
                if (OUTF32) Cf[off] = acc[mi][ni][r];
                else        Cb[off] = f2bf(acc[mi][ni][r]);
            }
        }
    }
}

// ---------------------------------------------------------------- phase (Lambda^e) * Bu, cumsum over batch (8), -> X bf16
__global__ void phase_cumsum(const unsigned short* __restrict__ Bu, const int* __restrict__ len,
                             const float* __restrict__ nu_log, const float* __restrict__ th_log,
                             unsigned short* __restrict__ X) {
    int t = blockIdx.x * 256 + threadIdx.x;   // [0, 2048*512)
    int n = t & 511;
    int l = t >> 9;
    float nu = __expf(nu_log[n]);     // exp(nu_log)
    float th = __expf(th_log[n]);     // lam_arg
    float sr = 0.f, si = 0.f;
#pragma unroll
    for (int b = 0; b < 8; ++b) {
        float e = fmaxf((float)(len[b] - (l + 1)), 0.0f);
        float mag = __expf(-e * nu);              // lam_mod^e
        float ang = e * th;
        float cs = cosf(ang);                      // accurate range reduction
        float sn = sinf(ang);
        float Lr = mag * cs, Li = mag * sn;
        size_t base = ((size_t)b * 2048 + l) * 1024;
        float br_ = bf2f(Bu[base + n]);
        float bi_ = bf2f(Bu[base + 512 + n]);
        sr += Lr * br_ - Li * bi_;
        si += Lr * bi_ + Li * br_;
        X[base + n]       = f2bf(sr);
        X[base + 512 + n] = f2bf(si);
    }
}

// ----------------------------------------------------------------
extern "C" void kernel_launch(void* const* d_in, const int* in_sizes, int n_in,
                              void* d_out, int out_size, void* d_ws, size_t ws_size,
                              hipStream_t stream) {
    const float* u      = (const float*)d_in[0];   // (8,2048,1024) f32
    const int*   len    = (const int*)d_in[1];     // (8,)
    const float* nu_log = (const float*)d_in[2];   // (512,)
    const float* th_log = (const float*)d_in[3];   // (512,)
    const float* Br     = (const float*)d_in[4];   // (1024,512)
    const float* Bi     = (const float*)d_in[5];   // (1024,512)
    const float* Cr     = (const float*)d_in[6];   // (512,1024)
    const float* Ci     = (const float*)d_in[7];   // (512,1024)
    float* y = (float*)d_out;                      // (8,2048,1024) f32

    char* ws = (char*)d_ws;
    unsigned short* A  = (unsigned short*)(ws);                 // 33,554,432 B  (u as bf16)
    unsigned short* Bu = (unsigned short*)(ws + 33554432);      // 33,554,432 B  (u@[Br|Bi] bf16)
    unsigned short* Bt = (unsigned short*)(ws + 67108864);      //  2,097,152 B
    unsigned short* Dt = (unsigned short*)(ws + 69206016);      //  2,097,152 B
    unsigned short* X  = A;   // reuse A's slot (dead after GEMM1)

    convert_u<<<16384, 256, 0, stream>>>((const float4*)u, A);
    build_bt<<<dim3(32, 32), dim3(32, 8), 0, stream>>>(Br, Bi, Bt);
    build_dt<<<dim3(32, 32), dim3(32, 8), 0, stream>>>(Cr, Ci, Dt);
    gemm_bt<0><<<dim3(8, 128), 256, 0, stream>>>(A, Bt, Bu, nullptr);
    phase_cumsum<<<4096, 256, 0, stream>>>(Bu, len, nu_log, th_log, X);
    gemm_bt<1><<<dim3(8, 128), 256, 0, stream>>>(X, Dt, nullptr, y);
}

// Round 2
// 240.671 us; speedup vs baseline: 1.0836x; 1.0836x over previous
//
#include <hip/hip_runtime.h>

typedef unsigned short ushort_t;
typedef short bf16x8 __attribute__((ext_vector_type(8)));
typedef float f32x4 __attribute__((ext_vector_type(4)));

__device__ __forceinline__ unsigned short f2bf(float f) {
    unsigned u = __float_as_uint(f);
    u += 0x7FFFu + ((u >> 16) & 1u);      // round-to-nearest-even
    return (unsigned short)(u >> 16);
}
__device__ __forceinline__ float bf2f(unsigned short h) {
    return __uint_as_float(((unsigned)h) << 16);
}

__device__ __forceinline__ void gload_lds16(const void* g, void* l) {
    __builtin_amdgcn_global_load_lds(
        (const __attribute__((address_space(1))) void*)g,
        (__attribute__((address_space(3))) void*)l,
        16, 0, 0);
}

// ---------------------------------------------------------------- convert u -> bf16
__global__ void convert_u(const float4* __restrict__ u, unsigned short* __restrict__ A) {
    int i = blockIdx.x * 256 + threadIdx.x;   // indexes float4, 4.19M total
    float4 v = u[i];
    ushort4 o;
    o.x = f2bf(v.x); o.y = f2bf(v.y); o.z = f2bf(v.z); o.w = f2bf(v.w);
    ((ushort4*)A)[i] = o;
}

// ---------------------------------------------------------------- Bt[n][k] = (n<512? Br[k][n] : Bi[k][n-512])
__global__ void build_bt(const float* __restrict__ Br, const float* __restrict__ Bi,
                         unsigned short* __restrict__ Bt) {
    __shared__ unsigned short tile[32][33];
    int bk = blockIdx.x * 32;   // k block
    int bn = blockIdx.y * 32;   // n block
    int tx = threadIdx.x;       // 0..31
    int ty = threadIdx.y;       // 0..7
    for (int i = ty; i < 32; i += 8) {
        int k = bk + i;
        int n = bn + tx;
        float v = (n < 512) ? Br[k * 512 + n] : Bi[k * 512 + (n - 512)];
        tile[tx][i] = f2bf(v);
    }
    __syncthreads();
    for (int i = ty; i < 32; i += 8) {
        int n = bn + i;
        int k = bk + tx;
        Bt[(size_t)n * 1024 + k] = tile[i][tx];
    }
}

// ---------------------------------------------------------------- Dt[h][k2] = (k2<512? Cr[k2][h] : -Ci[k2-512][h])
__global__ void build_dt(const float* __restrict__ Cr, const float* __restrict__ Ci,
                         unsigned short* __restrict__ Dt) {
    __shared__ unsigned short tile[32][33];
    int bk = blockIdx.x * 32;   // k2 block
    int bh = blockIdx.y * 32;   // h block
    int tx = threadIdx.x;
    int ty = threadIdx.y;
    for (int i = ty; i < 32; i += 8) {
        int k2 = bk + i;
        int h = bh + tx;
        float v = (k2 < 512) ? Cr[(size_t)k2 * 1024 + h] : -Ci[(size_t)(k2 - 512) * 1024 + h];
        tile[tx][i] = f2bf(v);
    }
    __syncthreads();
    for (int i = ty; i < 32; i += 8) {
        int h = bh + i;
        int k2 = bk + tx;
        Dt[(size_t)h * 1024 + k2] = tile[i][tx];
    }
}

// ---------------------------------------------------------------- GEMM: C(16384x1024) = A x Bt (B row = output col)
// m97 structure + XCD-aware swizzle: id%8 = XCD under round-robin dispatch;
// each XCD owns 16 contiguous A row-panels x all 8 col-blocks
// -> per-XCD working set = 4 MB A + 2 MB B ~= L2 capacity.
template <int OUTF32>
__global__ __launch_bounds__(256)
void gemm_bt(const unsigned short* __restrict__ A, const unsigned short* __restrict__ Bt,
             unsigned short* __restrict__ Cb, float* __restrict__ Cf) {
    __shared__ unsigned short As[128 * 32];   // [row][k] row-major, 8 KB
    __shared__ unsigned short Bs[128 * 32];   // [col][k] row-major, 8 KB

    const int tid  = threadIdx.x;
    const int wave = tid >> 6;
    const int lane = tid & 63;
    const int lm = lane & 15;
    const int lq = lane >> 4;
    const int wr = wave >> 1;   // 0..1
    const int wc = wave & 1;    // 0..1

    // XCD swizzle: linear id -> (panel, colblock) so id%8 (the XCD) picks the panel group
    const int id  = blockIdx.y * 8 + blockIdx.x;     // 0..1023
    const int xcd = id & 7;
    const int j   = id >> 3;                         // 0..127
    const int row0 = (xcd * 16 + (j >> 3)) * 128;    // 128 A-panels, 16 per XCD
    const int col0 = (j & 7) * 128;                  // 8 col-blocks

    f32x4 acc[4][4] = {};

    const int o0 = tid * 16;
    const int o1 = o0 + 4096;

    const char* gA0 = (const char*)A  + (size_t)(row0 + (o0 >> 6)) * 2048 + (o0 & 63);
    const char* gA1 = (const char*)A  + (size_t)(row0 + (o1 >> 6)) * 2048 + (o1 & 63);
    const char* gB0 = (const char*)Bt + (size_t)(col0 + (o0 >> 6)) * 2048 + (o0 & 63);
    const char* gB1 = (const char*)Bt + (size_t)(col0 + (o1 >> 6)) * 2048 + (o1 & 63);

    char* lA0 = (char*)As + wave * 1024;
    char* lA1 = lA0 + 4096;
    char* lB0 = (char*)Bs + wave * 1024;
    char* lB1 = lB0 + 4096;

    for (int kk = 0; kk < 32; ++kk) {
        __syncthreads();                 // previous iter's LDS reads done
        gload_lds16(gA0, lA0);
        gload_lds16(gA1, lA1);
        gload_lds16(gB0, lB0);
        gload_lds16(gB1, lB1);
        gA0 += 64; gA1 += 64; gB0 += 64; gB1 += 64;
        __syncthreads();                 // staging visible

        bf16x8 af[4], bfr[4];
#pragma unroll
        for (int mi = 0; mi < 4; ++mi) {
            int m = wr * 64 + mi * 16 + lm;
            af[mi] = *(const bf16x8*)(As + m * 32 + lq * 8);   // ds_read_b128
        }
#pragma unroll
        for (int ni = 0; ni < 4; ++ni) {
            int n = wc * 64 + ni * 16 + lm;
            bfr[ni] = *(const bf16x8*)(Bs + n * 32 + lq * 8);
        }
#pragma unroll
        for (int mi = 0; mi < 4; ++mi)
#pragma unroll
            for (int ni = 0; ni < 4; ++ni)
                acc[mi][ni] = __builtin_amdgcn_mfma_f32_16x16x32_bf16(
                    af[mi], bfr[ni], acc[mi][ni], 0, 0, 0);
    }

    // epilogue: C/D layout col=lane&15, row=(lane>>4)*4+reg  [m89/m91-verified]
#pragma unroll
    for (int mi = 0; mi < 4; ++mi) {
#pragma unroll
        for (int ni = 0; ni < 4; ++ni) {
            int c  = col0 + wc * 64 + ni * 16 + lm;
            int r0 = row0 + wr * 64 + mi * 16 + lq * 4;
#pragma unroll
            for (int r = 0; r < 4; ++r) {
                size_t off = (size_t)(r0 + r) * 1024 + c;
                if (OUTF32) Cf[off] = acc[mi][ni][r];
                else        Cb[off] = f2bf(acc[mi][ni][r]);
            }
        }
    }
}

// ---------------------------------------------------------------- phase (Lambda^e) * Bu, cumsum over batch (8), -> X bf16
// th = exp(theta_log) in (0, 2*pi) by construction -> rev = th/2pi in (0,1);
// (e*th) mod 2pi == fract(e*rev)*2pi exactly (e integer <= 2048), so fast
// __sincosf is safe: phase err ~8e-4 rad vs 0.023 absmax budget.
__global__ void phase_cumsum(const unsigned short* __restrict__ Bu, const int* __restrict__ len,
                             const float* __restrict__ nu_log, const float* __restrict__ th_log,
                             unsigned short* __restrict__ X) {
    int t = blockIdx.x * 256 + threadIdx.x;   // [0, 2048*512)
    int n = t & 511;
    int l = t >> 9;
    float nu  = __expf(nu_log[n]);                              // exp(nu_log)
    float rev = __expf(th_log[n]) * 0.15915494309189535f;       // lam_arg / 2pi
    float lp1 = (float)(l + 1);
    float sr = 0.f, si = 0.f;
#pragma unroll
    for (int b = 0; b < 8; ++b) {
        float e = fmaxf((float)len[b] - lp1, 0.0f);
        float mag = __expf(-e * nu);              // lam_mod^e
        float ar = e * rev;
        ar -= floorf(ar);                          // fract -> [0,1)
        float sn, cs;
        __sincosf(ar * 6.283185307179586f, &sn, &cs);
        float Lr = mag * cs, Li = mag * sn;
        size_t base = ((size_t)b * 2048 + l) * 1024;
        float br_ = bf2f(Bu[base + n]);
        float bi_ = bf2f(Bu[base + 512 + n]);
        sr += Lr * br_ - Li * bi_;
        si += Lr * bi_ + Li * br_;
        X[base + n]       = f2bf(sr);
        X[base + 512 + n] = f2bf(si);
    }
}

// ----------------------------------------------------------------
extern "C" void kernel_launch(void* const* d_in, const int* in_sizes, int n_in,
                              void* d_out, int out_size, void* d_ws, size_t ws_size,
                              hipStream_t stream) {
    const float* u      = (const float*)d_in[0];   // (8,2048,1024) f32
    const int*   len    = (const int*)d_in[1];     // (8,)
    const float* nu_log = (const float*)d_in[2];   // (512,)
    const float* th_log = (const float*)d_in[3];   // (512,)
    const float* Br     = (const float*)d_in[4];   // (1024,512)
    const float* Bi     = (const float*)d_in[5];   // (1024,512)
    const float* Cr     = (const float*)d_in[6];   // (512,1024)
    const float* Ci     = (const float*)d_in[7];   // (512,1024)
    float* y = (float*)d_out;                      // (8,2048,1024) f32

    char* ws = (char*)d_ws;
    unsigned short* A  = (unsigned short*)(ws);                 // 33,554,432 B  (u as bf16)
    unsigned short* Bu = (unsigned short*)(ws + 33554432);      // 33,554,432 B  (u@[Br|Bi] bf16)
    unsigned short* Bt = (unsigned short*)(ws + 67108864);      //  2,097,152 B
    unsigned short* Dt = (unsigned short*)(ws + 69206016);      //  2,097,152 B
    unsigned short* X  = A;   // reuse A's slot (dead after GEMM1)

    convert_u<<<16384, 256, 0, stream>>>((const float4*)u, A);
    build_bt<<<dim3(32, 32), dim3(32, 8), 0, stream>>>(Br, Bi, Bt);
    build_dt<<<dim3(32, 32), dim3(32, 8), 0, stream>>>(Cr, Ci, Dt);
    gemm_bt<0><<<dim3(8, 128), 256, 0, stream>>>(A, Bt, Bu, nullptr);
    phase_cumsum<<<4096, 256, 0, stream>>>(Bu, len, nu_log, th_log, X);
    gemm_bt<1><<<dim3(8, 128), 256, 0, stream>>>(X, Dt, nullptr, y);
}

// Round 3
// 224.630 us; speedup vs baseline: 1.1610x; 1.0714x over previous
//
#include <hip/hip_runtime.h>

typedef unsigned short ushort_t;
typedef short bf16x8 __attribute__((ext_vector_type(8)));
typedef float f32x4 __attribute__((ext_vector_type(4)));

__device__ __forceinline__ unsigned short f2bf(float f) {
    unsigned u = __float_as_uint(f);
    u += 0x7FFFu + ((u >> 16) & 1u);      // round-to-nearest-even
    return (unsigned short)(u >> 16);
}
__device__ __forceinline__ float bf2f(unsigned short h) {
    return __uint_as_float(((unsigned)h) << 16);
}

__device__ __forceinline__ void gload_lds16(const void* g, void* l) {
    __builtin_amdgcn_global_load_lds(
        (const __attribute__((address_space(1))) void*)g,
        (__attribute__((address_space(3))) void*)l,
        16, 0, 0);
}

// ---------------------------------------------------------------- convert u -> bf16
__global__ void convert_u(const float4* __restrict__ u, unsigned short* __restrict__ A) {
    int i = blockIdx.x * 256 + threadIdx.x;   // indexes float4, 4.19M total
    float4 v = u[i];
    ushort4 o;
    o.x = f2bf(v.x); o.y = f2bf(v.y); o.z = f2bf(v.z); o.w = f2bf(v.w);
    ((ushort4*)A)[i] = o;
}

// ---------------------------------------------------------------- build Bt and Dt (merged, z selects)
// Bt[n][k]  = (n<512 ? Br[k][n] : Bi[k][n-512])        (1024x1024 bf16)
// Dt[h][k2] = (k2<512 ? Cr[k2][h] : -Ci[k2-512][h])    (1024x1024 bf16)
__global__ void build_panels(const float* __restrict__ Br, const float* __restrict__ Bi,
                             const float* __restrict__ Cr, const float* __restrict__ Ci,
                             unsigned short* __restrict__ Bt, unsigned short* __restrict__ Dt) {
    __shared__ unsigned short tile[32][33];
    int bk = blockIdx.x * 32;   // k block
    int bn = blockIdx.y * 32;   // out-row block
    int tx = threadIdx.x;       // 0..31
    int ty = threadIdx.y;       // 0..7
    if (blockIdx.z == 0) {
        for (int i = ty; i < 32; i += 8) {
            int k = bk + i;
            int n = bn + tx;
            float v = (n < 512) ? Br[k * 512 + n] : Bi[k * 512 + (n - 512)];
            tile[tx][i] = f2bf(v);
        }
        __syncthreads();
        for (int i = ty; i < 32; i += 8)
            Bt[(size_t)(bn + i) * 1024 + bk + tx] = tile[i][tx];
    } else {
        for (int i = ty; i < 32; i += 8) {
            int k2 = bk + i;
            int h = bn + tx;
            float v = (k2 < 512) ? Cr[(size_t)k2 * 1024 + h] : -Ci[(size_t)(k2 - 512) * 1024 + h];
            tile[tx][i] = f2bf(v);
        }
        __syncthreads();
        for (int i = ty; i < 32; i += 8)
            Dt[(size_t)(bn + i) * 1024 + bk + tx] = tile[i][tx];
    }
}

// ---------------------------------------------------------------- GEMM: C(16384x1024) = A x Bt (B row = output col)
// Block tile 128x256, 4 waves (2x2), wave tile 64x128 (4x8 of 16x16x32 MFMA).
// Rationale: LDS-read pipe was the floor (0.5 b128/MFMA -> 27 us/GEMM);
// 64x128 wave tile gives 0.375 b128/MFMA -> 15.4 us floor, balanced vs MFMA 16.6.
// XCD swizzle: per-XCD round = 2 MB A-panels + 2 MB Bt = 4 MB ~= L2.
template <int OUTF32>
__global__ __launch_bounds__(256, 2)
void gemm_bt(const unsigned short* __restrict__ A, const unsigned short* __restrict__ Bt,
             unsigned short* __restrict__ Cb, float* __restrict__ Cf) {
    __shared__ unsigned short As[128 * 32];   // [row][k], 8 KB
    __shared__ unsigned short Bs[256 * 32];   // [col][k], 16 KB

    const int tid  = threadIdx.x;
    const int wave = tid >> 6;
    const int lane = tid & 63;
    const int lm = lane & 15;
    const int lq = lane >> 4;
    const int wr = wave >> 1;   // 0..1  (64-row slab)
    const int wc = wave & 1;    // 0..1  (128-col slab)

    // XCD swizzle: 512 blocks; id%8 = XCD under round-robin dispatch
    const int id  = blockIdx.x;          // 0..511
    const int xcd = id & 7;
    const int j   = id >> 3;             // 0..63
    const int row0 = (xcd * 16 + (j >> 2)) * 128;   // 128 row-panels, 16/XCD
    const int col0 = (j & 3) * 256;                 // 4 col-blocks

    f32x4 acc[4][8] = {};

    // staging byte offsets: A = 8 KB (2 issues), B = 16 KB (4 issues)
    const int o = tid * 16;
    const char* gA0 = (const char*)A  + (size_t)(row0 + (o >> 6)) * 2048 + (o & 63);
    const char* gA1 = gA0 + 64 * 2048;                      // +4096 bytes of tile
    const char* gB0 = (const char*)Bt + (size_t)(col0 + (o >> 6)) * 2048 + (o & 63);
    const char* gB1 = gB0 + 64 * 2048;
    const char* gB2 = gB1 + 64 * 2048;
    const char* gB3 = gB2 + 64 * 2048;

    char* lA0 = (char*)As + wave * 1024;
    char* lA1 = lA0 + 4096;
    char* lB0 = (char*)Bs + wave * 1024;
    char* lB1 = lB0 + 4096;
    char* lB2 = lB1 + 4096;
    char* lB3 = lB2 + 4096;

    for (int kk = 0; kk < 32; ++kk) {
        __syncthreads();                 // previous iter's LDS reads done
        gload_lds16(gA0, lA0);
        gload_lds16(gA1, lA1);
        gload_lds16(gB0, lB0);
        gload_lds16(gB1, lB1);
        gload_lds16(gB2, lB2);
        gload_lds16(gB3, lB3);
        gA0 += 64; gA1 += 64; gB0 += 64; gB1 += 64; gB2 += 64; gB3 += 64;
        __syncthreads();                 // staging visible

        bf16x8 af[4], bfr[8];
#pragma unroll
        for (int mi = 0; mi < 4; ++mi) {
            int m = wr * 64 + mi * 16 + lm;
            af[mi] = *(const bf16x8*)(As + m * 32 + lq * 8);   // ds_read_b128
        }
#pragma unroll
        for (int ni = 0; ni < 8; ++ni) {
            int n = wc * 128 + ni * 16 + lm;
            bfr[ni] = *(const bf16x8*)(Bs + n * 32 + lq * 8);
        }
#pragma unroll
        for (int mi = 0; mi < 4; ++mi)
#pragma unroll
            for (int ni = 0; ni < 8; ++ni)
                acc[mi][ni] = __builtin_amdgcn_mfma_f32_16x16x32_bf16(
                    af[mi], bfr[ni], acc[mi][ni], 0, 0, 0);
    }

    // epilogue: C/D layout col=lane&15, row=(lane>>4)*4+reg  [m89/m91-verified]
#pragma unroll
    for (int mi = 0; mi < 4; ++mi) {
#pragma unroll
        for (int ni = 0; ni < 8; ++ni) {
            int c  = col0 + wc * 128 + ni * 16 + lm;
            int r0 = row0 + wr * 64 + mi * 16 + lq * 4;
#pragma unroll
            for (int r = 0; r < 4; ++r) {
                size_t off = (size_t)(r0 + r) * 1024 + c;
                if (OUTF32) Cf[off] = acc[mi][ni][r];
                else        Cb[off] = f2bf(acc[mi][ni][r]);
            }
        }
    }
}

// ---------------------------------------------------------------- phase (Lambda^e) * Bu, cumsum over batch (8), IN PLACE on Bu
// th = exp(theta_log) in (0,2pi) -> rev in (0,1); (e*th) mod 2pi == fract(e*rev)*2pi
// exactly (e integer <= 2048) -> fast __sincosf safe (~8e-4 rad vs 0.023 budget).
// Vectorized: 4 consecutive n per thread, ushort4 (8 B) accesses.
__global__ void phase_cumsum(unsigned short* __restrict__ Bu, const int* __restrict__ len,
                             const float* __restrict__ nu_log, const float* __restrict__ th_log) {
    int t = blockIdx.x * 256 + threadIdx.x;   // [0, 2048*128)
    int n4 = (t & 127) * 4;
    int l = t >> 7;
    float4 nul = ((const float4*)nu_log)[n4 >> 2];
    float4 thl = ((const float4*)th_log)[n4 >> 2];
    float nu[4]  = { __expf(nul.x), __expf(nul.y), __expf(nul.z), __expf(nul.w) };
    const float inv2pi = 0.15915494309189535f;
    float rv[4]  = { __expf(thl.x) * inv2pi, __expf(thl.y) * inv2pi,
                     __expf(thl.z) * inv2pi, __expf(thl.w) * inv2pi };
    float lp1 = (float)(l + 1);
    float sr[4] = {0.f, 0.f, 0.f, 0.f}, si[4] = {0.f, 0.f, 0.f, 0.f};
#pragma unroll
    for (int b = 0; b < 8; ++b) {
        float e = fmaxf((float)len[b] - lp1, 0.0f);
        size_t base = ((size_t)b * 2048 + l) * 1024;
        ushort4 br4 = *(const ushort4*)(Bu + base + n4);
        ushort4 bi4 = *(const ushort4*)(Bu + base + 512 + n4);
        unsigned short orr[4], oii[4];
        const unsigned short brr[4] = {br4.x, br4.y, br4.z, br4.w};
        const unsigned short bii[4] = {bi4.x, bi4.y, bi4.z, bi4.w};
#pragma unroll
        for (int q = 0; q < 4; ++q) {
            float mag = __expf(-e * nu[q]);
            float ar = e * rv[q];
            ar -= floorf(ar);
            float sn, cs;
            __sincosf(ar * 6.283185307179586f, &sn, &cs);
            float Lr = mag * cs, Li = mag * sn;
            float br_ = bf2f(brr[q]);
            float bi_ = bf2f(bii[q]);
            sr[q] += Lr * br_ - Li * bi_;
            si[q] += Lr * bi_ + Li * br_;
            orr[q] = f2bf(sr[q]);
            oii[q] = f2bf(si[q]);
        }
        *(ushort4*)(Bu + base + n4)       = make_ushort4(orr[0], orr[1], orr[2], orr[3]);
        *(ushort4*)(Bu + base + 512 + n4) = make_ushort4(oii[0], oii[1], oii[2], oii[3]);
    }
}

// ----------------------------------------------------------------
extern "C" void kernel_launch(void* const* d_in, const int* in_sizes, int n_in,
                              void* d_out, int out_size, void* d_ws, size_t ws_size,
                              hipStream_t stream) {
    const float* u      = (const float*)d_in[0];   // (8,2048,1024) f32
    const int*   len    = (const int*)d_in[1];     // (8,)
    const float* nu_log = (const float*)d_in[2];   // (512,)
    const float* th_log = (const float*)d_in[3];   // (512,)
    const float* Br     = (const float*)d_in[4];   // (1024,512)
    const float* Bi     = (const float*)d_in[5];   // (1024,512)
    const float* Cr     = (const float*)d_in[6];   // (512,1024)
    const float* Ci     = (const float*)d_in[7];   // (512,1024)
    float* y = (float*)d_out;                      // (8,2048,1024) f32

    char* ws = (char*)d_ws;
    unsigned short* A  = (unsigned short*)(ws);                 // 33,554,432 B  (u as bf16)
    unsigned short* Bu = (unsigned short*)(ws + 33554432);      // 33,554,432 B  (Bu, then X in place)
    unsigned short* Bt = (unsigned short*)(ws + 67108864);      //  2,097,152 B
    unsigned short* Dt = (unsigned short*)(ws + 69206016);      //  2,097,152 B

    convert_u<<<16384, 256, 0, stream>>>((const float4*)u, A);
    build_panels<<<dim3(32, 32, 2), dim3(32, 8), 0, stream>>>(Br, Bi, Cr, Ci, Bt, Dt);
    gemm_bt<0><<<512, 256, 0, stream>>>(A, Bt, Bu, nullptr);
    phase_cumsum<<<1024, 256, 0, stream>>>(Bu, len, nu_log, th_log);
    gemm_bt<1><<<512, 256, 0, stream>>>(Bu, Dt, nullptr, y);
}

// Round 4
// 224.171 us; speedup vs baseline: 1.1634x; 1.0020x over previous
//
#include <hip/hip_runtime.h>

typedef short bf16x8 __attribute__((ext_vector_type(8)));
typedef float f32x4 __attribute__((ext_vector_type(4)));

__device__ __forceinline__ unsigned short f2bf(float f) {
    unsigned u = __float_as_uint(f);
    u += 0x7FFFu + ((u >> 16) & 1u);      // round-to-nearest-even
    return (unsigned short)(u >> 16);
}
__device__ __forceinline__ float bf2f(unsigned short h) {
    return __uint_as_float(((unsigned)h) << 16);
}
__device__ __forceinline__ void gload_lds16(const void* g, void* l) {
    __builtin_amdgcn_global_load_lds(
        (const __attribute__((address_space(1))) void*)g,
        (__attribute__((address_space(3))) void*)l,
        16, 0, 0);
}

// ---------------------------------------------------------------- prep (one launch):
// blocks [0,16384): convert u -> bf16 A' with ROW PERMUTATION
//   A'[p*128 + b*16 + ll] = u[b*2048 + p*16 + ll]   (so GEMM1 block p holds all 8 b at 16 l's)
// blocks [16384,17408): Bt[j][k] interleaved:  g=j>>5, w=j&31, n=g*16+(w&15)
//   Bt[j][k] = (w<16 ? Br[k][n] : Bi[k][n])          (1024x1024 bf16)
// blocks [17408,18432): Dt[h][j] interleaved:  Dt[h][j] = (w<16 ? Cr[n][h] : -Ci[n][h])
__global__ void prep(const float* __restrict__ u,
                     const float* __restrict__ Br, const float* __restrict__ Bi,
                     const float* __restrict__ Cr, const float* __restrict__ Ci,
                     unsigned short* __restrict__ A, unsigned short* __restrict__ Bt,
                     unsigned short* __restrict__ Dt) {
    int bid = blockIdx.x;
    if (bid < 16384) {
        int i = bid * 256 + threadIdx.x;        // float4 id, out-order
        int ro = i >> 8, c4 = i & 255;          // out row (permuted), col-group
        int p = ro >> 7, b = (ro >> 4) & 7, ll = ro & 15;
        int ri = b * 2048 + p * 16 + ll;        // source row in u
        float4 v = ((const float4*)u)[(size_t)ri * 256 + c4];
        ushort4 o; o.x = f2bf(v.x); o.y = f2bf(v.y); o.z = f2bf(v.z); o.w = f2bf(v.w);
        ((ushort4*)A)[i] = o;
        return;
    }
    __shared__ unsigned short tile[32][33];
    int id = bid - 16384;          // [0, 2048)
    int z  = id >> 10;             // 0: Bt, 1: Dt
    int t  = id & 1023;
    int jt = t >> 5, kt = t & 31;  // j-tile (32 cols of out), k/h-tile
    int tx = threadIdx.x & 31, ty = threadIdx.x >> 5;   // 32 x 8
    if (z == 0) {
        for (int i2 = ty; i2 < 32; i2 += 8) {          // i2 = k offset
            int k = kt * 32 + i2;
            float v = (tx < 16) ? Br[(size_t)k * 512 + jt * 16 + tx]
                                : Bi[(size_t)k * 512 + jt * 16 + (tx & 15)];
            tile[tx][i2] = f2bf(v);                    // tile[w][k]
        }
        __syncthreads();
        for (int i2 = ty; i2 < 32; i2 += 8)            // i2 = w
            Bt[(size_t)(jt * 32 + i2) * 1024 + kt * 32 + tx] = tile[i2][tx];
    } else {
        for (int i2 = ty; i2 < 32; i2 += 8) {          // i2 = w
            float v = (i2 < 16) ? Cr[(size_t)(jt * 16 + i2) * 1024 + kt * 32 + tx]
                                : -Ci[(size_t)(jt * 16 + (i2 & 15)) * 1024 + kt * 32 + tx];
            tile[i2][tx] = f2bf(v);                    // tile[w][h]
        }
        __syncthreads();
        for (int i2 = ty; i2 < 32; i2 += 8)            // i2 = h offset
            Dt[(size_t)(kt * 32 + i2) * 1024 + jt * 32 + tx] = tile[tx][i2];
    }
}

// ---------------------------------------------------------------- GEMM1 + fused phase/cumsum
// Block tile 128x256 over A'(16384x1024 bf16, permuted rows) x Bt. 4 waves 2x2,
// wave tile 64x128. Epilogue: p_b = Lambda^e * Bu (fp32 acc), prefix-sum over b
// (mi in-register; wr=0 -> wr=1 via LDS), store X bf16 in STANDARD (b*2048+l) rows
// and interleaved cols (matching Dt's k-order).
__global__ __launch_bounds__(256, 2)
void gemm1_fused(const unsigned short* __restrict__ A, const unsigned short* __restrict__ Bt,
                 const int* __restrict__ len, const float* __restrict__ nu_log,
                 const float* __restrict__ th_log, unsigned short* __restrict__ X) {
    __shared__ unsigned short As[128 * 32];   // 8 KB
    __shared__ unsigned short Bs[256 * 32];   // 16 KB (reused as fp32 totals in epilogue)

    const int tid = threadIdx.x, wave = tid >> 6, lane = tid & 63;
    const int lm = lane & 15, lq = lane >> 4;
    const int wr = wave >> 1, wc = wave & 1;

    const int id = blockIdx.x, xcd = id & 7, j = id >> 3;
    const int p    = xcd * 16 + (j >> 2);   // l-panel: l in [p*16, p*16+16)
    const int row0 = p * 128;               // permuted-A row base
    const int col0 = (j & 3) * 256;

    f32x4 acc[4][8] = {};

    const int o = tid * 16;
    const char* gA0 = (const char*)A  + (size_t)(row0 + (o >> 6)) * 2048 + (o & 63);
    const char* gA1 = gA0 + 64 * 2048;
    const char* gB0 = (const char*)Bt + (size_t)(col0 + (o >> 6)) * 2048 + (o & 63);
    const char* gB1 = gB0 + 64 * 2048;
    const char* gB2 = gB1 + 64 * 2048;
    const char* gB3 = gB2 + 64 * 2048;
    char* lA0 = (char*)As + wave * 1024; char* lA1 = lA0 + 4096;
    char* lB0 = (char*)Bs + wave * 1024; char* lB1 = lB0 + 4096;
    char* lB2 = lB1 + 4096;              char* lB3 = lB2 + 4096;

    for (int kk = 0; kk < 32; ++kk) {
        __syncthreads();
        gload_lds16(gA0, lA0); gload_lds16(gA1, lA1);
        gload_lds16(gB0, lB0); gload_lds16(gB1, lB1);
        gload_lds16(gB2, lB2); gload_lds16(gB3, lB3);
        gA0 += 64; gA1 += 64; gB0 += 64; gB1 += 64; gB2 += 64; gB3 += 64;
        __syncthreads();

        bf16x8 af[4], bfr[8];
#pragma unroll
        for (int mi = 0; mi < 4; ++mi) {
            int m = wr * 64 + mi * 16 + lm;
            af[mi] = *(const bf16x8*)(As + m * 32 + lq * 8);
        }
#pragma unroll
        for (int ni = 0; ni < 8; ++ni) {
            int n = wc * 128 + ni * 16 + lm;
            bfr[ni] = *(const bf16x8*)(Bs + n * 32 + lq * 8);
        }
#pragma unroll
        for (int mi = 0; mi < 4; ++mi)
#pragma unroll
            for (int ni = 0; ni < 8; ++ni)
                acc[mi][ni] = __builtin_amdgcn_mfma_f32_16x16x32_bf16(
                    af[mi], bfr[ni], acc[mi][ni], 0, 0, 0);
    }

    // ---- fused epilogue ----
    __syncthreads();                        // K-loop LDS reads complete; Bs reusable
    float* tot = (float*)Bs;                // [wc][32][64 lanes] fp32, 16 KB
    const float inv2pi = 0.15915494309189535f;
    const float twopi  = 6.283185307179586f;

    int lenv[8];
#pragma unroll
    for (int b = 0; b < 8; ++b) lenv[b] = len[b];
    float nuv[4], rvv[4];
#pragma unroll
    for (int g = 0; g < 4; ++g) {
        int n = (col0 >> 1) + wc * 64 + g * 16 + lm;
        nuv[g] = __expf(nu_log[n]);
        rvv[g] = __expf(th_log[n]) * inv2pi;
    }
    const int l_lo = p * 16 + lq * 4;

    if (wr == 0) {
#pragma unroll
        for (int g = 0; g < 4; ++g) {
#pragma unroll
            for (int r = 0; r < 4; ++r) {
                float sr = 0.f, si = 0.f;
                int l = l_lo + r;
                float lp1 = (float)(l + 1);
#pragma unroll
                for (int mi = 0; mi < 4; ++mi) {
                    int b = mi;                           // wr==0: b = 0..3
                    float e = fmaxf((float)lenv[b] - lp1, 0.f);
                    float mag = __expf(-e * nuv[g]);
                    float ar = e * rvv[g]; ar -= floorf(ar);
                    float sn, cs; __sincosf(ar * twopi, &sn, &cs);
                    float Lr = mag * cs, Li = mag * sn;
                    float Bur = acc[mi][2 * g][r], Bui = acc[mi][2 * g + 1][r];
                    sr += Lr * Bur - Li * Bui;
                    si += Lr * Bui + Li * Bur;
                    size_t rowoff = ((size_t)b * 2048 + l) * 1024;
                    int c = col0 + wc * 128 + g * 32 + lm;
                    X[rowoff + c]      = f2bf(sr);
                    X[rowoff + c + 16] = f2bf(si);
                }
                int f = (g * 4 + r) * 2;
                tot[(wc * 32 + f) * 64 + lane]     = sr;
                tot[(wc * 32 + f + 1) * 64 + lane] = si;
            }
        }
    }
    __syncthreads();
    if (wr == 1) {
#pragma unroll
        for (int g = 0; g < 4; ++g) {
#pragma unroll
            for (int r = 0; r < 4; ++r) {
                int f = (g * 4 + r) * 2;
                float sr = tot[(wc * 32 + f) * 64 + lane];
                float si = tot[(wc * 32 + f + 1) * 64 + lane];
                int l = l_lo + r;
                float lp1 = (float)(l + 1);
#pragma unroll
                for (int mi = 0; mi < 4; ++mi) {
                    int b = 4 + mi;                       // wr==1: b = 4..7
                    float e = fmaxf((float)lenv[b] - lp1, 0.f);
                    float mag = __expf(-e * nuv[g]);
                    float ar = e * rvv[g]; ar -= floorf(ar);
                    float sn, cs; __sincosf(ar * twopi, &sn, &cs);
                    float Lr = mag * cs, Li = mag * sn;
                    float Bur = acc[mi][2 * g][r], Bui = acc[mi][2 * g + 1][r];
                    sr += Lr * Bur - Li * Bui;
                    si += Lr * Bui + Li * Bur;
                    size_t rowoff = ((size_t)b * 2048 + l) * 1024;
                    int c = col0 + wc * 128 + g * 32 + lm;
                    X[rowoff + c]      = f2bf(sr);
                    X[rowoff + c + 16] = f2bf(si);
                }
            }
        }
    }
}

// ---------------------------------------------------------------- GEMM2: y(16384x1024 f32) = X(bf16) x Dt (row = output col h)
__global__ __launch_bounds__(256, 2)
void gemm2(const unsigned short* __restrict__ X, const unsigned short* __restrict__ Dt,
           float* __restrict__ Y) {
    __shared__ unsigned short As[128 * 32];
    __shared__ unsigned short Bs[256 * 32];

    const int tid = threadIdx.x, wave = tid >> 6, lane = tid & 63;
    const int lm = lane & 15, lq = lane >> 4;
    const int wr = wave >> 1, wc = wave & 1;

    const int id = blockIdx.x, xcd = id & 7, j = id >> 3;
    const int row0 = (xcd * 16 + (j >> 2)) * 128;
    const int col0 = (j & 3) * 256;

    f32x4 acc[4][8] = {};

    const int o = tid * 16;
    const char* gA0 = (const char*)X  + (size_t)(row0 + (o >> 6)) * 2048 + (o & 63);
    const char* gA1 = gA0 + 64 * 2048;
    const char* gB0 = (const char*)Dt + (size_t)(col0 + (o >> 6)) * 2048 + (o & 63);
    const char* gB1 = gB0 + 64 * 2048;
    const char* gB2 = gB1 + 64 * 2048;
    const char* gB3 = gB2 + 64 * 2048;
    char* lA0 = (char*)As + wave * 1024; char* lA1 = lA0 + 4096;
    char* lB0 = (char*)Bs + wave * 1024; char* lB1 = lB0 + 4096;
    char* lB2 = lB1 + 4096;              char* lB3 = lB2 + 4096;

    for (int kk = 0; kk < 32; ++kk) {
        __syncthreads();
        gload_lds16(gA0, lA0); gload_lds16(gA1, lA1);
        gload_lds16(gB0, lB0); gload_lds16(gB1, lB1);
        gload_lds16(gB2, lB2); gload_lds16(gB3, lB3);
        gA0 += 64; gA1 += 64; gB0 += 64; gB1 += 64; gB2 += 64; gB3 += 64;
        __syncthreads();

        bf16x8 af[4], bfr[8];
#pragma unroll
        for (int mi = 0; mi < 4; ++mi) {
            int m = wr * 64 + mi * 16 + lm;
            af[mi] = *(const bf16x8*)(As + m * 32 + lq * 8);
        }
#pragma unroll
        for (int ni = 0; ni < 8; ++ni) {
            int n = wc * 128 + ni * 16 + lm;
            bfr[ni] = *(const bf16x8*)(Bs + n * 32 + lq * 8);
        }
#pragma unroll
        for (int mi = 0; mi < 4; ++mi)
#pragma unroll
            for (int ni = 0; ni < 8; ++ni)
                acc[mi][ni] = __builtin_amdgcn_mfma_f32_16x16x32_bf16(
                    af[mi], bfr[ni], acc[mi][ni], 0, 0, 0);
    }

#pragma unroll
    for (int mi = 0; mi < 4; ++mi) {
#pragma unroll
        for (int ni = 0; ni < 8; ++ni) {
            int c  = col0 + wc * 128 + ni * 16 + lm;
            int r0 = row0 + wr * 64 + mi * 16 + lq * 4;
#pragma unroll
            for (int r = 0; r < 4; ++r)
                Y[(size_t)(r0 + r) * 1024 + c] = acc[mi][ni][r];
        }
    }
}

// ----------------------------------------------------------------
extern "C" void kernel_launch(void* const* d_in, const int* in_sizes, int n_in,
                              void* d_out, int out_size, void* d_ws, size_t ws_size,
                              hipStream_t stream) {
    const float* u      = (const float*)d_in[0];   // (8,2048,1024) f32
    const int*   len    = (const int*)d_in[1];     // (8,)
    const float* nu_log = (const float*)d_in[2];   // (512,)
    const float* th_log = (const float*)d_in[3];   // (512,)
    const float* Br     = (const float*)d_in[4];   // (1024,512)
    const float* Bi     = (const float*)d_in[5];   // (1024,512)
    const float* Cr     = (const float*)d_in[6];   // (512,1024)
    const float* Ci     = (const float*)d_in[7];   // (512,1024)
    float* y = (float*)d_out;                      // (8,2048,1024) f32

    char* ws = (char*)d_ws;
    unsigned short* A  = (unsigned short*)(ws);                 // 33.5 MB  (u bf16, rows permuted)
    unsigned short* X  = (unsigned short*)(ws + 33554432);      // 33.5 MB  (phase+cumsum result)
    unsigned short* Bt = (unsigned short*)(ws + 67108864);      //  2 MB
    unsigned short* Dt = (unsigned short*)(ws + 69206016);      //  2 MB

    prep<<<18432, 256, 0, stream>>>(u, Br, Bi, Cr, Ci, A, Bt, Dt);
    gemm1_fused<<<512, 256, 0, stream>>>(A, Bt, len, nu_log, th_log, X);
    gemm2<<<512, 256, 0, stream>>>(X, Dt, y);
}